// Round 5
// baseline (18584.216 us; speedup 1.0000x reference)
//
#include <hip/hip_runtime.h>

#define HID 64
#define NF 8

typedef float f2 __attribute__((ext_vector_type(2)));
typedef float f4 __attribute__((ext_vector_type(4)));

__device__ __forceinline__ float tanh_fast(float x) {
  float ax = fabsf(x);
  float e = __expf(-2.0f * ax);
  float r = __fdividef(1.0f - e, 1.0f + e);
  return x < 0.0f ? -r : r;
}
__device__ __forceinline__ float act_gate(float x, bool is_tanh_lane) {
  float e = __expf(-x);
  float s = __fdividef(1.0f, 1.0f + e);
  float t = tanh_fast(x);
  return is_tanh_lane ? t : s;
}
template <int CTRL>
__device__ __forceinline__ float qp(float x) {
  return __int_as_float(
      __builtin_amdgcn_update_dpp(0, __float_as_int(x), CTRL, 0xF, 0xF, true));
}

// 256 threads = 4 waves, 1 wave/SIMD (launch_bounds(256,1) -> 512 VGPR budget).
// Waves 0,1: layer-0 LSTM (32 units each) + head + IO. Waves 2,3: layer-1.
// Pipelined: phase t computes h0[t] and h1[t-1]; ONE barrier per phase.
// Dots: K split 4-way across each quad (lane k reads only K-chunk k), gate
// rows in rotated order (lane k row j = gate (k+j)&3) so the quad all-reduce
// is 3 quad_perm DPPs with compile-time register indices. Chunk reads are
// bank-skewed by lane (rot k / 2k) -> 4 distinct bank groups, conflict-free.
// All weights overlaid in one f2 wreg[128] (~300 VGPR).
__global__ __launch_bounds__(256, 1) void decoder_p4(
    const float* __restrict__ h0in, const float* __restrict__ c0in,
    const float* __restrict__ diffp, const float* __restrict__ target,
    const float* __restrict__ Wih0, const float* __restrict__ Whh0,
    const float* __restrict__ bih0, const float* __restrict__ bhh0,
    const float* __restrict__ Wih1, const float* __restrict__ Whh1,
    const float* __restrict__ bih1, const float* __restrict__ bhh1,
    const float* __restrict__ Whid, const float* __restrict__ bhidp,
    const float* __restrict__ Woutp, const float* __restrict__ boutp,
    float* __restrict__ outp, const int T)
{
  const int tid = threadIdx.x;
  const int wv  = tid >> 6;
  const int l   = tid & 63;
  const int q   = l >> 2;
  const int k   = l & 3;
  const bool isL1 = (wv >= 2);
  const int uA  = 32 * (wv & 1) + 2 * q;
  const int uB  = uA + 1;
  const bool isk0 = (k == 0);
  const bool isg  = (k == 2);

  __shared__ alignas(256) float h0r[2][64];
  __shared__ alignas(256) float h1r[2][64];
  __shared__ alignas(256) float hidS[2][32];
  __shared__ alignas(256) float obuf[64 * NF];
  __shared__ alignas(256) float tbuf[2][32 * NF];

  f2 wreg[128];
  float b_A = 0.f, b_B = 0.f;
  float xdA = 0.f, xdB = 0.f;
  float bhA = 0.f, bhB = 0.f, bo_ = 0.f;

  if (isL1) {
    // L1: lane K-range [32k, 32k+32) of [h0; h1]; k<2 -> Wih1, k>=2 -> Whh1
    #pragma unroll
    for (int i = 0; i < 2; ++i) {
      const int u = uA + i;
      #pragma unroll
      for (int j = 0; j < 4; ++j) {
        const int row = 64 * ((k + j) & 3) + u;
        const float* Wsrc = (k < 2) ? Wih1 : Whh1;
        const float* rp = Wsrc + row * HID + 32 * (k & 1);
        #pragma unroll
        for (int c = 0; c < 8; ++c) {
          const int cc = (c + 2 * k) & 7;
          f4 v = *(const f4*)(rp + 4 * cc);
          wreg[(i * 4 + j) * 16 + 2 * c]     = v.lo;
          wreg[(i * 4 + j) * 16 + 2 * c + 1] = v.hi;
        }
      }
    }
    b_A = bih1[64 * k + uA] + bhh1[64 * k + uA];
    b_B = bih1[64 * k + uB] + bhh1[64 * k + uB];
  } else {
    // L0: lane K-range [16k, 16k+16) of h0prev
    #pragma unroll
    for (int i = 0; i < 2; ++i) {
      const int u = uA + i;
      #pragma unroll
      for (int j = 0; j < 4; ++j) {
        const int row = 64 * ((k + j) & 3) + u;
        const float* rp = Whh0 + row * HID + 16 * k;
        #pragma unroll
        for (int c = 0; c < 4; ++c) {
          const int cc = (c + k) & 3;
          f4 v = *(const f4*)(rp + 4 * cc);
          wreg[(i * 4 + j) * 8 + 2 * c]     = v.lo;
          wreg[(i * 4 + j) * 8 + 2 * c + 1] = v.hi;
        }
      }
    }
    b_A = bih0[64 * k + uA] + bhh0[64 * k + uA];
    b_B = bih0[64 * k + uB] + bhh0[64 * k + uB];
    {
      const float* ra = Wih0 + (64 * k + uA) * 14;
      const float* rb = Wih0 + (64 * k + uB) * 14;
      #pragma unroll
      for (int c = 0; c < 4; ++c) {
        wreg[80 + c] = (f2){ra[2 * c], ra[2 * c + 1]};
        wreg[84 + c] = (f2){rb[2 * c], rb[2 * c + 1]};
      }
      #pragma unroll
      for (int m = 0; m < 6; ++m) {
        xdA += ra[8 + m] * diffp[m];
        xdB += rb[8 + m] * diffp[m];
      }
    }
    if (wv == 0) {
      // hid rows 2q, 2q+1; K-chunk [16k,16k+16)
      #pragma unroll
      for (int i = 0; i < 2; ++i) {
        const float* rp = Whid + (2 * q + i) * HID + 16 * k;
        #pragma unroll
        for (int c = 0; c < 4; ++c) {
          const int cc = (c + k) & 3;
          f4 v = *(const f4*)(rp + 4 * cc);
          wreg[64 + i * 8 + 2 * c]     = v.lo;
          wreg[64 + i * 8 + 2 * c + 1] = v.hi;
        }
      }
      bhA = bhidp[2 * q];
      bhB = bhidp[2 * q + 1];
    } else if (q < 8) {
      // out row q; K-chunk [8k, 8k+8)
      const float* rp = Woutp + q * 32 + 8 * k;
      #pragma unroll
      for (int c = 0; c < 2; ++c) {
        const int cc = (c + k) & 1;
        f4 v = *(const f4*)(rp + 4 * cc);
        wreg[64 + 2 * c]     = v.lo;
        wreg[64 + 2 * c + 1] = v.hi;
      }
      bo_ = boutp[q];
    }
  }

  float cA = 0.f, cB = 0.f, hA = 0.f, hB = 0.f;
  if (isk0) {
    if (!isL1) { cA = c0in[uA]; cB = c0in[uB]; }
    else       { cA = c0in[64 + uA]; cB = c0in[64 + uB]; }
  }
  if (wv == 0) h0r[1][l] = h0in[l];
  else if (wv == 1) h1r[1][l] = h0in[64 + l];
  else if (wv == 2) {
    *(f4*)&((float*)tbuf)[l * 8]     = *(const f4*)&target[l * 8];
    *(f4*)&((float*)tbuf)[l * 8 + 4] = *(const f4*)&target[l * 8 + 4];
  }
  float xcA = 0.f, xcB = 0.f;
  __syncthreads();

  const int tend = T + 2;
  for (int t = 0; t <= tend; ++t) {
    const int p = t & 1;
    if (!isL1) {
      // ---------- layer 0: h0[t] ----------
      if (t < T) {
        const float* hp = &h0r[p ^ 1][16 * k];
        f2 P[8];
        #pragma unroll
        for (int z = 0; z < 8; ++z) P[z] = (f2){0.f, 0.f};
        #pragma unroll
        for (int c = 0; c < 4; ++c) {
          f4 v = *(const f4*)(hp + 4 * ((c + k) & 3));
          #pragma unroll
          for (int ij = 0; ij < 8; ++ij) {
            P[ij] += wreg[ij * 8 + 2 * c] * v.lo;
            P[ij] += wreg[ij * 8 + 2 * c + 1] * v.hi;
          }
        }
        float pA0 = P[0].x + P[0].y, pA1 = P[1].x + P[1].y;
        float pA2 = P[2].x + P[2].y, pA3 = P[3].x + P[3].y;
        float pB0 = P[4].x + P[4].y, pB1 = P[5].x + P[5].y;
        float pB2 = P[6].x + P[6].y, pB3 = P[7].x + P[7].y;
        float gA = ((pA0 + qp<0x39>(pA3)) + (qp<0x4E>(pA2) + qp<0x93>(pA1))) + b_A + xcA;
        float gB = ((pB0 + qp<0x39>(pB3)) + (qp<0x4E>(pB2) + qp<0x93>(pB1))) + b_B + xcB;
        float aA = act_gate(gA, isg);
        float aB = act_gate(gB, isg);
        float A1 = qp<0xB1>(aA), A2 = qp<0x4E>(aA), A3 = qp<0x1B>(aA);
        float B1 = qp<0xB1>(aB), B2 = qp<0x4E>(aB), B3 = qp<0x1B>(aB);
        if (isk0) {
          cA = A1 * cA + aA * A2;
          cB = B1 * cB + aB * B2;
          hA = A3 * tanh_fast(cA);
          hB = B3 * tanh_fast(cB);
          *(f2*)&h0r[p][uA] = (f2){hA, hB};
        }
      }
      // ---------- x-proj for phase t+1 ----------
      if (t < T - 1) {
        const f4* trow = (const f4*)&tbuf[(t >> 5) & 1][(t & 31) * NF];
        f4 r0 = trow[0], r1 = trow[1];
        f2 sa = wreg[80] * r0.lo; sa += wreg[81] * r0.hi;
        sa += wreg[82] * r1.lo;  sa += wreg[83] * r1.hi;
        f2 sb = wreg[84] * r0.lo; sb += wreg[85] * r0.hi;
        sb += wreg[86] * r1.lo;  sb += wreg[87] * r1.hi;
        xcA = xdA + sa.x + sa.y;
        xcB = xdB + sb.x + sb.y;
      } else { xcA = 0.f; xcB = 0.f; }
      // ---------- wave0: hid(t-2) ----------
      if (wv == 0 && t >= 2 && t <= T + 1) {
        const float* hp = &h1r[p][16 * k];
        f2 pa = {0.f, 0.f}, pb = {0.f, 0.f};
        #pragma unroll
        for (int c = 0; c < 4; ++c) {
          f4 v = *(const f4*)(hp + 4 * ((c + k) & 3));
          pa += wreg[64 + 2 * c] * v.lo; pa += wreg[64 + 2 * c + 1] * v.hi;
          pb += wreg[72 + 2 * c] * v.lo; pb += wreg[72 + 2 * c + 1] * v.hi;
        }
        float sa = pa.x + pa.y; sa += qp<0xB1>(sa); sa += qp<0x4E>(sa);
        float sb = pb.x + pb.y; sb += qp<0xB1>(sb); sb += qp<0x4E>(sb);
        if (isk0) *(f2*)&hidS[p][2 * q] = (f2){sa + bhA, sb + bhB};
      }
      // ---------- wave1: out(t-3) + IO ----------
      if (wv == 1) {
        if (q < 8 && t >= 3 && t <= T + 2) {
          const float* hp = &hidS[p ^ 1][8 * k];
          f2 po = {0.f, 0.f};
          #pragma unroll
          for (int c = 0; c < 2; ++c) {
            f4 v = *(const f4*)(hp + 4 * ((c + k) & 1));
            po += wreg[64 + 2 * c] * v.lo; po += wreg[64 + 2 * c + 1] * v.hi;
          }
          float so = po.x + po.y; so += qp<0xB1>(so); so += qp<0x4E>(so);
          if (isk0) obuf[((t - 3) & 63) * NF + q] = rintf(so + bo_);
        }
        if (l >= 32) {
          const int j = l - 32;
          if ((t & 31) == 4 && t >= 36) {
            #pragma unroll
            for (int ii = 0; ii < 2; ++ii) {
              const int fidx = 2 * j + ii;
              const int s = (t - 36) + (fidx >> 1);
              const int c4 = (fidx & 1) * 4;
              *(f4*)&outp[s * NF + c4] = *(const f4*)&obuf[(s & 63) * NF + c4];
            }
          }
          if ((t & 31) == 12) {
            const int cl = (t >> 5) + 1;
            if (cl * 32 < T) {
              #pragma unroll
              for (int ii = 0; ii < 2; ++ii) {
                const int off = (2 * j + ii) * 4;
                *(f4*)&tbuf[cl & 1][off] = *(const f4*)&target[cl * 256 + off];
              }
            }
          }
        }
      }
    } else {
      // ---------- layer 1: h1[t-1] ----------
      if (t >= 1 && t <= T) {
        const float* base = (k < 2) ? &h0r[p ^ 1][32 * (k & 1)]
                                    : &h1r[p][32 * (k & 1)];
        f2 P[8];
        #pragma unroll
        for (int z = 0; z < 8; ++z) P[z] = (f2){0.f, 0.f};
        #pragma unroll
        for (int c = 0; c < 8; ++c) {
          f4 v = *(const f4*)(base + 4 * ((c + 2 * k) & 7));
          #pragma unroll
          for (int ij = 0; ij < 8; ++ij) {
            P[ij] += wreg[ij * 16 + 2 * c] * v.lo;
            P[ij] += wreg[ij * 16 + 2 * c + 1] * v.hi;
          }
        }
        float pA0 = P[0].x + P[0].y, pA1 = P[1].x + P[1].y;
        float pA2 = P[2].x + P[2].y, pA3 = P[3].x + P[3].y;
        float pB0 = P[4].x + P[4].y, pB1 = P[5].x + P[5].y;
        float pB2 = P[6].x + P[6].y, pB3 = P[7].x + P[7].y;
        float gA = ((pA0 + qp<0x39>(pA3)) + (qp<0x4E>(pA2) + qp<0x93>(pA1))) + b_A;
        float gB = ((pB0 + qp<0x39>(pB3)) + (qp<0x4E>(pB2) + qp<0x93>(pB1))) + b_B;
        float aA = act_gate(gA, isg);
        float aB = act_gate(gB, isg);
        float A1 = qp<0xB1>(aA), A2 = qp<0x4E>(aA), A3 = qp<0x1B>(aA);
        float B1 = qp<0xB1>(aB), B2 = qp<0x4E>(aB), B3 = qp<0x1B>(aB);
        if (isk0) {
          cA = A1 * cA + aA * A2;
          cB = B1 * cB + aB * B2;
          hA = A3 * tanh_fast(cA);
          hB = B3 * tanh_fast(cB);
          *(f2*)&h1r[p ^ 1][uA] = (f2){hA, hB};
        }
      }
    }
    __syncthreads();
  }

  // ================= EPILOGUE =================
  {
    const int tlast = tend - ((tend - 4) & 31);
    const int s0 = tlast - 4;
    for (int idx = tid; idx < (T - s0) * NF; idx += 256) {
      const int s = s0 + (idx >> 3);
      outp[s * NF + (idx & 7)] = obuf[(s & 63) * NF + (idx & 7)];
    }
  }
  if (isk0) {
    const int base = T * NF;
    if (!isL1) {
      *(f2*)&outp[base + uA]       = (f2){hA, hB};   // h_final layer 0
      *(f2*)&outp[base + 128 + uA] = (f2){cA, cB};   // c_final layer 0
    } else {
      *(f2*)&outp[base + 64 + uA]  = (f2){hA, hB};   // h_final layer 1
      *(f2*)&outp[base + 192 + uA] = (f2){cA, cB};   // c_final layer 1
    }
  }
}

extern "C" void kernel_launch(void* const* d_in, const int* in_sizes, int n_in,
                              void* d_out, int out_size, void* d_ws, size_t ws_size,
                              hipStream_t stream) {
  const float* h0in   = (const float*)d_in[1];
  const float* c0in   = (const float*)d_in[2];
  const float* diffp  = (const float*)d_in[3];
  const float* target = (const float*)d_in[4];
  const float* Wih0   = (const float*)d_in[5];
  const float* Whh0   = (const float*)d_in[6];
  const float* bih0   = (const float*)d_in[7];
  const float* bhh0   = (const float*)d_in[8];
  const float* Wih1   = (const float*)d_in[9];
  const float* Whh1   = (const float*)d_in[10];
  const float* bih1   = (const float*)d_in[11];
  const float* bhh1   = (const float*)d_in[12];
  const float* Whid   = (const float*)d_in[13];
  const float* bhidp  = (const float*)d_in[14];
  const float* Woutp  = (const float*)d_in[15];
  const float* boutp  = (const float*)d_in[16];
  float* outp = (float*)d_out;
  const int T = in_sizes[4] / NF;

  decoder_p4<<<dim3(1), dim3(256), 0, stream>>>(
      h0in, c0in, diffp, target,
      Wih0, Whh0, bih0, bhh0,
      Wih1, Whh1, bih1, bhh1,
      Whid, bhidp, Woutp, boutp,
      outp, T);
}

// Round 6
// 13866.231 us; speedup vs baseline: 1.3403x; 1.3403x over previous
//
#include <hip/hip_runtime.h>

#define HID 64
#define NF 8

typedef float f2 __attribute__((ext_vector_type(2)));
typedef float f4 __attribute__((ext_vector_type(4)));

__device__ __forceinline__ float tanh_fast(float x) {
  float ax = fabsf(x);
  float e = __expf(-2.0f * ax);
  float r = __fdividef(1.0f - e, 1.0f + e);
  return x < 0.0f ? -r : r;
}
__device__ __forceinline__ float act_gate(float x, bool is_tanh_lane) {
  float e = __expf(-x);
  float s = __fdividef(1.0f, 1.0f + e);
  float t = tanh_fast(x);
  return is_tanh_lane ? t : s;
}
template <int CTRL>
__device__ __forceinline__ float qp(float x) {
  return __int_as_float(
      __builtin_amdgcn_update_dpp(0, __float_as_int(x), CTRL, 0xF, 0xF, true));
}

// 512 threads = 8 waves, 2/SIMD (256 VGPR budget). Waves 0-3: layer-0 (+head,
// IO, x-proj). Waves 4-7: layer-1. Pipeline: phase t computes h0[t] and
// h1[t-1]; ONE barrier/phase (R4 schedule). Dots use R5's proven quad scheme:
// one unit per quad, K split 4-way across the quad's lanes (lane k reads only
// K-chunk k, bank-skewed rotation -> conflict-free), gate rows in rotated
// order (lane k row j = gate (k+j)&3) so the gate all-reduce is 3 quad_perm
// DPPs with compile-time indices; activation exchange = 3 more quad_perms;
// k==0 lane keeps exact fp32 c,h. Per-lane weights: L1 128 floats, L0 ~104.
__global__ __launch_bounds__(512, 2) void decoder_p6(
    const float* __restrict__ h0in, const float* __restrict__ c0in,
    const float* __restrict__ diffp, const float* __restrict__ target,
    const float* __restrict__ Wih0, const float* __restrict__ Whh0,
    const float* __restrict__ bih0, const float* __restrict__ bhh0,
    const float* __restrict__ Wih1, const float* __restrict__ Whh1,
    const float* __restrict__ bih1, const float* __restrict__ bhh1,
    const float* __restrict__ Whid, const float* __restrict__ bhidp,
    const float* __restrict__ Woutp, const float* __restrict__ boutp,
    float* __restrict__ outp, const int T)
{
  const int tid = threadIdx.x;
  const int wv  = tid >> 6;
  const int l   = tid & 63;
  const int q   = l >> 2;
  const int k   = l & 3;
  const bool isL1 = (wv >= 4);
  const int u   = 16 * (wv & 3) + q;   // hidden unit (this quad's)
  const int r   = 64 * k + u;          // final gate row for this lane
  const bool isk0 = (k == 0);
  const bool isg  = (k == 2);

  __shared__ alignas(256) float h0r[2][64];
  __shared__ alignas(256) float h1r[2][64];
  __shared__ alignas(256) float hidS[2][32];
  __shared__ alignas(256) float obuf[64 * NF];
  __shared__ alignas(256) float tbuf[2][32 * NF];

  f2 wreg[64];
  float b_ = 0.f, xd = 0.f;
  float bhA = 0.f, bhB = 0.f, bo_ = 0.f;

  if (isL1) {
    // L1: K-chunk k of [h0;h1] (C=32). k<2 -> Wih1 half, k>=2 -> Whh1 half.
    const float* Wsrc = (k < 2) ? Wih1 : Whh1;
    const int co = 32 * (k & 1);
    #pragma unroll
    for (int j = 0; j < 4; ++j) {
      const int row = 64 * ((k + j) & 3) + u;
      const float* rp = Wsrc + row * HID + co;
      #pragma unroll
      for (int c = 0; c < 8; ++c) {
        f4 v = *(const f4*)(rp + 4 * ((c + 2 * k) & 7));
        wreg[16 * j + 2 * c]     = v.lo;
        wreg[16 * j + 2 * c + 1] = v.hi;
      }
    }
    b_ = bih1[r] + bhh1[r];
  } else {
    // L0: K-chunk k of h0prev (C=16)
    #pragma unroll
    for (int j = 0; j < 4; ++j) {
      const int row = 64 * ((k + j) & 3) + u;
      const float* rp = Whh0 + row * HID + 16 * k;
      #pragma unroll
      for (int c = 0; c < 4; ++c) {
        f4 v = *(const f4*)(rp + 4 * ((c + k) & 3));
        wreg[8 * j + 2 * c]     = v.lo;
        wreg[8 * j + 2 * c + 1] = v.hi;
      }
    }
    b_ = bih0[r] + bhh0[r];
    {
      const float* ra = Wih0 + r * 14;
      #pragma unroll
      for (int c = 0; c < 4; ++c) wreg[48 + c] = (f2){ra[2 * c], ra[2 * c + 1]};
      #pragma unroll
      for (int m = 0; m < 6; ++m) xd += ra[8 + m] * diffp[m];
    }
    if (wv == 0) {
      // head stage 1 weights: hid rows 2q, 2q+1, K-chunk [16k,16k+16)
      #pragma unroll
      for (int i = 0; i < 2; ++i) {
        const float* rp = Whid + (2 * q + i) * HID + 16 * k;
        #pragma unroll
        for (int c = 0; c < 4; ++c) {
          f4 v = *(const f4*)(rp + 4 * ((c + k) & 3));
          wreg[32 + 8 * i + 2 * c]     = v.lo;
          wreg[32 + 8 * i + 2 * c + 1] = v.hi;
        }
      }
      bhA = bhidp[2 * q];
      bhB = bhidp[2 * q + 1];
    } else if (wv == 1 && q < 8) {
      // head stage 2 weights: out row q, K-chunk [8k, 8k+8)
      const float* rp = Woutp + q * 32 + 8 * k;
      #pragma unroll
      for (int c = 0; c < 2; ++c) {
        f4 v = *(const f4*)(rp + 4 * ((c + k) & 1));
        wreg[32 + 2 * c]     = v.lo;
        wreg[32 + 2 * c + 1] = v.hi;
      }
      bo_ = boutp[q];
    }
  }

  float cS = 0.f, hS = 0.f;
  if (isk0) cS = isL1 ? c0in[64 + u] : c0in[u];
  if (wv == 0) h0r[1][l] = h0in[l];
  else if (wv == 1) h1r[1][l] = h0in[64 + l];
  else if (wv == 2) {
    *(f4*)&((float*)tbuf)[l * 8]     = *(const f4*)&target[l * 8];
    *(f4*)&((float*)tbuf)[l * 8 + 4] = *(const f4*)&target[l * 8 + 4];
  }
  float xc = 0.f;   // x(0) = zeros
  __syncthreads();

  const int tend = T + 2;
  for (int t = 0; t <= tend; ++t) {
    const int p = t & 1;
    if (isL1) {
      // ---------- layer 1: h1[t-1] = cell(h0[t-1], h1[t-2]) ----------
      if (t >= 1 && t <= T) {
        const float* base = (k < 2) ? &h0r[p ^ 1][32 * (k & 1)]
                                    : &h1r[p][32 * (k & 1)];
        f2 P0 = {0.f,0.f}, P1 = {0.f,0.f}, P2 = {0.f,0.f}, P3 = {0.f,0.f};
        #pragma unroll
        for (int c = 0; c < 8; ++c) {
          f4 v = *(const f4*)(base + 4 * ((c + 2 * k) & 7));
          P0 += wreg[2*c] * v.lo;      P0 += wreg[2*c+1] * v.hi;
          P1 += wreg[16+2*c] * v.lo;   P1 += wreg[16+2*c+1] * v.hi;
          P2 += wreg[32+2*c] * v.lo;   P2 += wreg[32+2*c+1] * v.hi;
          P3 += wreg[48+2*c] * v.lo;   P3 += wreg[48+2*c+1] * v.hi;
        }
        float p0 = P0.x + P0.y, p1 = P1.x + P1.y;
        float p2 = P2.x + P2.y, p3 = P3.x + P3.y;
        float g = ((p0 + qp<0x39>(p3)) + (qp<0x4E>(p2) + qp<0x93>(p1))) + b_;
        float a = act_gate(g, isg);
        float A1 = qp<0xB1>(a), A2 = qp<0x4E>(a), A3 = qp<0x1B>(a);
        if (isk0) {
          cS = A1 * cS + a * A2;
          hS = A3 * tanh_fast(cS);
          h1r[p ^ 1][u] = hS;
        }
      }
    } else {
      // ---------- layer 0: h0[t] = cell(x(t), h0[t-1]) ----------
      if (t < T) {
        const float* base = &h0r[p ^ 1][16 * k];
        f2 P0 = {0.f,0.f}, P1 = {0.f,0.f}, P2 = {0.f,0.f}, P3 = {0.f,0.f};
        #pragma unroll
        for (int c = 0; c < 4; ++c) {
          f4 v = *(const f4*)(base + 4 * ((c + k) & 3));
          P0 += wreg[2*c] * v.lo;      P0 += wreg[2*c+1] * v.hi;
          P1 += wreg[8+2*c] * v.lo;    P1 += wreg[8+2*c+1] * v.hi;
          P2 += wreg[16+2*c] * v.lo;   P2 += wreg[16+2*c+1] * v.hi;
          P3 += wreg[24+2*c] * v.lo;   P3 += wreg[24+2*c+1] * v.hi;
        }
        float p0 = P0.x + P0.y, p1 = P1.x + P1.y;
        float p2 = P2.x + P2.y, p3 = P3.x + P3.y;
        float g = ((p0 + qp<0x39>(p3)) + (qp<0x4E>(p2) + qp<0x93>(p1))) + b_ + xc;
        float a = act_gate(g, isg);
        float A1 = qp<0xB1>(a), A2 = qp<0x4E>(a), A3 = qp<0x1B>(a);
        if (isk0) {
          cS = A1 * cS + a * A2;
          hS = A3 * tanh_fast(cS);
          h0r[p][u] = hS;
        }
      }
      // ---------- x-proj for phase t+1 (uses target[t]) ----------
      if (t < T - 1) {
        const f4* trow = (const f4*)&tbuf[(t >> 5) & 1][(t & 31) * NF];
        f4 r0 = trow[0], r1 = trow[1];
        f2 s = wreg[48] * r0.lo; s += wreg[49] * r0.hi;
        s += wreg[50] * r1.lo;   s += wreg[51] * r1.hi;
        xc = xd + s.x + s.y;
      } else xc = 0.f;
      // ---------- wave0: hid(t-2) from h1[t-2] ----------
      if (wv == 0 && t >= 2 && t <= T + 1) {
        const float* hp = &h1r[p][16 * k];
        f2 pa = {0.f,0.f}, pb = {0.f,0.f};
        #pragma unroll
        for (int c = 0; c < 4; ++c) {
          f4 v = *(const f4*)(hp + 4 * ((c + k) & 3));
          pa += wreg[32+2*c] * v.lo; pa += wreg[32+2*c+1] * v.hi;
          pb += wreg[40+2*c] * v.lo; pb += wreg[40+2*c+1] * v.hi;
        }
        float sa = pa.x + pa.y; sa += qp<0xB1>(sa); sa += qp<0x4E>(sa);
        float sb = pb.x + pb.y; sb += qp<0xB1>(sb); sb += qp<0x4E>(sb);
        if (isk0) *(f2*)&hidS[p][2 * q] = (f2){sa + bhA, sb + bhB};
      }
      // ---------- wave1: out(t-3) + IO ----------
      if (wv == 1) {
        if (q < 8 && t >= 3 && t <= T + 2) {
          const float* hp = &hidS[p ^ 1][8 * k];
          f2 po = {0.f,0.f};
          #pragma unroll
          for (int c = 0; c < 2; ++c) {
            f4 v = *(const f4*)(hp + 4 * ((c + k) & 1));
            po += wreg[32+2*c] * v.lo; po += wreg[32+2*c+1] * v.hi;
          }
          float so = po.x + po.y; so += qp<0xB1>(so); so += qp<0x4E>(so);
          if (isk0) obuf[((t - 3) & 63) * NF + q] = rintf(so + bo_);
        }
        if (l >= 32) {
          const int j = l - 32;
          if ((t & 31) == 4 && t >= 36) {
            #pragma unroll
            for (int ii = 0; ii < 2; ++ii) {
              const int fidx = 2 * j + ii;
              const int s = (t - 36) + (fidx >> 1);
              const int c4 = (fidx & 1) * 4;
              *(f4*)&outp[s * NF + c4] = *(const f4*)&obuf[(s & 63) * NF + c4];
            }
          }
          if ((t & 31) == 12) {
            const int cl = (t >> 5) + 1;
            if (cl * 32 < T) {
              #pragma unroll
              for (int ii = 0; ii < 2; ++ii) {
                const int off = (2 * j + ii) * 4;
                *(f4*)&tbuf[cl & 1][off] = *(const f4*)&target[cl * 256 + off];
              }
            }
          }
        }
      }
    }
    __syncthreads();
  }

  // ================= EPILOGUE =================
  {
    const int tlast = tend - ((tend - 4) & 31);   // largest t<=tend, t%32==4
    const int s0 = tlast - 4;
    for (int idx = tid; idx < (T - s0) * NF; idx += 512) {
      const int s = s0 + (idx >> 3);
      outp[s * NF + (idx & 7)] = obuf[(s & 63) * NF + (idx & 7)];
    }
  }
  if (isk0) {
    const int base = T * NF;
    if (!isL1) {
      outp[base + u]        = hS;   // h_final layer 0
      outp[base + 128 + u]  = cS;   // c_final layer 0
    } else {
      outp[base + 64 + u]   = hS;   // h_final layer 1
      outp[base + 192 + u]  = cS;   // c_final layer 1
    }
  }
}

extern "C" void kernel_launch(void* const* d_in, const int* in_sizes, int n_in,
                              void* d_out, int out_size, void* d_ws, size_t ws_size,
                              hipStream_t stream) {
  const float* h0in   = (const float*)d_in[1];
  const float* c0in   = (const float*)d_in[2];
  const float* diffp  = (const float*)d_in[3];
  const float* target = (const float*)d_in[4];
  const float* Wih0   = (const float*)d_in[5];
  const float* Whh0   = (const float*)d_in[6];
  const float* bih0   = (const float*)d_in[7];
  const float* bhh0   = (const float*)d_in[8];
  const float* Wih1   = (const float*)d_in[9];
  const float* Whh1   = (const float*)d_in[10];
  const float* bih1   = (const float*)d_in[11];
  const float* bhh1   = (const float*)d_in[12];
  const float* Whid   = (const float*)d_in[13];
  const float* bhidp  = (const float*)d_in[14];
  const float* Woutp  = (const float*)d_in[15];
  const float* boutp  = (const float*)d_in[16];
  float* outp = (float*)d_out;
  const int T = in_sizes[4] / NF;

  decoder_p6<<<dim3(1), dim3(512), 0, stream>>>(
      h0in, c0in, diffp, target,
      Wih0, Whh0, bih0, bhh0,
      Wih1, Whh1, bih1, bhh1,
      Whid, bhidp, Woutp, boutp,
      outp, T);
}

// Round 7
// 13221.156 us; speedup vs baseline: 1.4056x; 1.0488x over previous
//
#include <hip/hip_runtime.h>

#define HID 64
#define NF 8

typedef float f2 __attribute__((ext_vector_type(2)));
typedef float f4 __attribute__((ext_vector_type(4)));

template <int CTRL>
__device__ __forceinline__ float qp(float x) {
  return __int_as_float(
      __builtin_amdgcn_update_dpp(0, __float_as_int(x), CTRL, 0xF, 0xF, true));
}

// 512 threads = 8 waves, 2/SIMD. Waves 0-3: layer-0 (+head, IO, x-proj).
// Waves 4-7: layer-1 (one step behind). R6's validated quad dataflow, with:
//  * split-group sync: LDS atomic phase counters instead of s_barrier.
//    L0 wave at phase t waits cnt0>=4t && cnt1>=4(t-1)  (1 phase of slack);
//    L1 wave waits cnt0>=4t && cnt1>=4t. Release-add after own LDS writes.
//    -> no vmcnt drain at sync, no 8-wave convoy; h0 roundtrip off L1's path.
//  * 4-deep rings (h0r,h1r,hidS) make the skew safe (checked per buffer).
//  * single-exp activations: tanh(x) = 2*sigma(2x)-1 with per-lane (am,ab).
// Head lags: hid(t-3) on wv0, out(t-4) on wv1.
__global__ __launch_bounds__(512, 2) void decoder_p7(
    const float* __restrict__ h0in, const float* __restrict__ c0in,
    const float* __restrict__ diffp, const float* __restrict__ target,
    const float* __restrict__ Wih0, const float* __restrict__ Whh0,
    const float* __restrict__ bih0, const float* __restrict__ bhh0,
    const float* __restrict__ Wih1, const float* __restrict__ Whh1,
    const float* __restrict__ bih1, const float* __restrict__ bhh1,
    const float* __restrict__ Whid, const float* __restrict__ bhidp,
    const float* __restrict__ Woutp, const float* __restrict__ boutp,
    float* __restrict__ outp, const int T)
{
  const int tid = threadIdx.x;
  const int wv  = tid >> 6;
  const int l   = tid & 63;
  const int q   = l >> 2;
  const int k   = l & 3;
  const bool isL1 = (wv >= 4);
  const int u   = 16 * (wv & 3) + q;   // hidden unit (this quad's)
  const int r   = 64 * k + u;          // final gate row for this lane
  const bool isk0 = (k == 0);
  const bool isg  = (k == 2);
  const float am = isg ? 2.0f : 1.0f;  // act: y=am*x, a=am*sigma(y)+ab
  const float ab = isg ? -1.0f : 0.0f;

  __shared__ alignas(256) float h0r[4][64];
  __shared__ alignas(256) float h1r[4][64];
  __shared__ alignas(256) float hidS[4][32];
  __shared__ alignas(256) float obuf[64 * NF];
  __shared__ alignas(256) float tbuf[2][32 * NF];
  __shared__ int cnt[2];

  f2 wreg[64];
  float b_ = 0.f, xd = 0.f;
  float bhA = 0.f, bhB = 0.f, bo_ = 0.f;

  if (isL1) {
    const float* Wsrc = (k < 2) ? Wih1 : Whh1;
    const int co = 32 * (k & 1);
    #pragma unroll
    for (int j = 0; j < 4; ++j) {
      const int row = 64 * ((k + j) & 3) + u;
      const float* rp = Wsrc + row * HID + co;
      #pragma unroll
      for (int c = 0; c < 8; ++c) {
        f4 v = *(const f4*)(rp + 4 * ((c + 2 * k) & 7));
        wreg[16 * j + 2 * c]     = v.lo;
        wreg[16 * j + 2 * c + 1] = v.hi;
      }
    }
    b_ = bih1[r] + bhh1[r];
  } else {
    #pragma unroll
    for (int j = 0; j < 4; ++j) {
      const int row = 64 * ((k + j) & 3) + u;
      const float* rp = Whh0 + row * HID + 16 * k;
      #pragma unroll
      for (int c = 0; c < 4; ++c) {
        f4 v = *(const f4*)(rp + 4 * ((c + k) & 3));
        wreg[8 * j + 2 * c]     = v.lo;
        wreg[8 * j + 2 * c + 1] = v.hi;
      }
    }
    b_ = bih0[r] + bhh0[r];
    {
      const float* ra = Wih0 + r * 14;
      #pragma unroll
      for (int c = 0; c < 4; ++c) wreg[48 + c] = (f2){ra[2 * c], ra[2 * c + 1]};
      #pragma unroll
      for (int m = 0; m < 6; ++m) xd += ra[8 + m] * diffp[m];
    }
    if (wv == 0) {
      #pragma unroll
      for (int i = 0; i < 2; ++i) {
        const float* rp = Whid + (2 * q + i) * HID + 16 * k;
        #pragma unroll
        for (int c = 0; c < 4; ++c) {
          f4 v = *(const f4*)(rp + 4 * ((c + k) & 3));
          wreg[32 + 8 * i + 2 * c]     = v.lo;
          wreg[32 + 8 * i + 2 * c + 1] = v.hi;
        }
      }
      bhA = bhidp[2 * q];
      bhB = bhidp[2 * q + 1];
    } else if (wv == 1 && q < 8) {
      const float* rp = Woutp + q * 32 + 8 * k;
      #pragma unroll
      for (int c = 0; c < 2; ++c) {
        f4 v = *(const f4*)(rp + 4 * ((c + k) & 1));
        wreg[32 + 2 * c]     = v.lo;
        wreg[32 + 2 * c + 1] = v.hi;
      }
      bo_ = boutp[q];
    }
  }

  float cS = 0.f, hS = 0.f;
  if (isk0) cS = isL1 ? c0in[64 + u] : c0in[u];
  // seeds in slot 3 (= states at t-1 for t=0 reads)
  if (wv == 0) h0r[3][l] = h0in[l];
  else if (wv == 1) h1r[3][l] = h0in[64 + l];
  else if (wv == 2) {
    *(f4*)&((float*)tbuf)[l * 8]     = *(const f4*)&target[l * 8];
    *(f4*)&((float*)tbuf)[l * 8 + 4] = *(const f4*)&target[l * 8 + 4];
  }
  if (tid == 0) { cnt[0] = 0; cnt[1] = 0; }
  float xc = 0.f;   // x(0) = zeros
  __syncthreads();

  int tgt  = 0;     // 4t
  int tgtm = -4;    // 4(t-1)
  const int tend = T + 3;
  for (int t = 0; t <= tend; ++t) {
    // ---- split-group wait ----
    if (!isL1) {
      while (__hip_atomic_load(&cnt[0], __ATOMIC_ACQUIRE, __HIP_MEMORY_SCOPE_WORKGROUP) < tgt)  {}
      while (__hip_atomic_load(&cnt[1], __ATOMIC_ACQUIRE, __HIP_MEMORY_SCOPE_WORKGROUP) < tgtm) {}
    } else {
      while (__hip_atomic_load(&cnt[0], __ATOMIC_ACQUIRE, __HIP_MEMORY_SCOPE_WORKGROUP) < tgt)  {}
      while (__hip_atomic_load(&cnt[1], __ATOMIC_ACQUIRE, __HIP_MEMORY_SCOPE_WORKGROUP) < tgt)  {}
    }
    const int sR0 = (t - 1) & 3;   // h0[t-1]
    if (isL1) {
      // ---------- layer 1: h1[t-1] = cell(h0[t-1], h1[t-2]) ----------
      if (t >= 1 && t <= T) {
        const int sR1 = (t - 2) & 3;
        const float* base = (k < 2) ? &h0r[sR0][32 * (k & 1)]
                                    : &h1r[sR1][32 * (k & 1)];
        f2 P0 = {0.f,0.f}, P1 = {0.f,0.f}, P2 = {0.f,0.f}, P3 = {0.f,0.f};
        #pragma unroll
        for (int c = 0; c < 8; ++c) {
          f4 v = *(const f4*)(base + 4 * ((c + 2 * k) & 7));
          P0 += wreg[2*c] * v.lo;      P0 += wreg[2*c+1] * v.hi;
          P1 += wreg[16+2*c] * v.lo;   P1 += wreg[16+2*c+1] * v.hi;
          P2 += wreg[32+2*c] * v.lo;   P2 += wreg[32+2*c+1] * v.hi;
          P3 += wreg[48+2*c] * v.lo;   P3 += wreg[48+2*c+1] * v.hi;
        }
        float p0 = P0.x + P0.y, p1 = P1.x + P1.y;
        float p2 = P2.x + P2.y, p3 = P3.x + P3.y;
        float g = ((p0 + qp<0x39>(p3)) + (qp<0x4E>(p2) + qp<0x93>(p1))) + b_;
        float e = __expf(-g * am);
        float s = __fdividef(1.0f, 1.0f + e);
        float a = fmaf(s, am, ab);
        float A1 = qp<0xB1>(a), A2 = qp<0x4E>(a), A3 = qp<0x1B>(a);
        if (isk0) {
          cS = A1 * cS + a * A2;
          float e2 = __expf(-2.0f * cS);
          hS = A3 * (__fdividef(2.0f, 1.0f + e2) - 1.0f);
          h1r[(t - 1) & 3][u] = hS;
        }
      }
    } else {
      // ---------- layer 0: h0[t] = cell(x(t), h0[t-1]) ----------
      if (t < T) {
        const float* base = &h0r[sR0][16 * k];
        f2 P0 = {0.f,0.f}, P1 = {0.f,0.f}, P2 = {0.f,0.f}, P3 = {0.f,0.f};
        #pragma unroll
        for (int c = 0; c < 4; ++c) {
          f4 v = *(const f4*)(base + 4 * ((c + k) & 3));
          P0 += wreg[2*c] * v.lo;      P0 += wreg[2*c+1] * v.hi;
          P1 += wreg[8+2*c] * v.lo;    P1 += wreg[8+2*c+1] * v.hi;
          P2 += wreg[16+2*c] * v.lo;   P2 += wreg[16+2*c+1] * v.hi;
          P3 += wreg[24+2*c] * v.lo;   P3 += wreg[24+2*c+1] * v.hi;
        }
        float p0 = P0.x + P0.y, p1 = P1.x + P1.y;
        float p2 = P2.x + P2.y, p3 = P3.x + P3.y;
        float g = ((p0 + qp<0x39>(p3)) + (qp<0x4E>(p2) + qp<0x93>(p1))) + b_ + xc;
        float e = __expf(-g * am);
        float s = __fdividef(1.0f, 1.0f + e);
        float a = fmaf(s, am, ab);
        float A1 = qp<0xB1>(a), A2 = qp<0x4E>(a), A3 = qp<0x1B>(a);
        if (isk0) {
          cS = A1 * cS + a * A2;
          float e2 = __expf(-2.0f * cS);
          hS = A3 * (__fdividef(2.0f, 1.0f + e2) - 1.0f);
          h0r[t & 3][u] = hS;
        }
      }
      // ---------- x-proj for phase t+1 (uses target[t]) ----------
      if (t < T - 1) {
        const f4* trow = (const f4*)&tbuf[(t >> 5) & 1][(t & 31) * NF];
        f4 r0 = trow[0], r1 = trow[1];
        f2 s = wreg[48] * r0.lo; s += wreg[49] * r0.hi;
        s += wreg[50] * r1.lo;   s += wreg[51] * r1.hi;
        xc = xd + s.x + s.y;
      } else xc = 0.f;
      // ---------- wave0: hid(t-3) from h1[t-3] ----------
      if (wv == 0 && t >= 3 && t <= T + 2) {
        const float* hp = &h1r[(t - 3) & 3][16 * k];
        f2 pa = {0.f,0.f}, pb = {0.f,0.f};
        #pragma unroll
        for (int c = 0; c < 4; ++c) {
          f4 v = *(const f4*)(hp + 4 * ((c + k) & 3));
          pa += wreg[32+2*c] * v.lo; pa += wreg[32+2*c+1] * v.hi;
          pb += wreg[40+2*c] * v.lo; pb += wreg[40+2*c+1] * v.hi;
        }
        float sa = pa.x + pa.y; sa += qp<0xB1>(sa); sa += qp<0x4E>(sa);
        float sb = pb.x + pb.y; sb += qp<0xB1>(sb); sb += qp<0x4E>(sb);
        if (isk0) *(f2*)&hidS[t & 3][2 * q] = (f2){sa + bhA, sb + bhB};
      }
      // ---------- wave1: out(t-4) + IO ----------
      if (wv == 1) {
        if (q < 8 && t >= 4) {
          const float* hp = &hidS[(t - 1) & 3][8 * k];
          f2 po = {0.f,0.f};
          #pragma unroll
          for (int c = 0; c < 2; ++c) {
            f4 v = *(const f4*)(hp + 4 * ((c + k) & 1));
            po += wreg[32+2*c] * v.lo; po += wreg[32+2*c+1] * v.hi;
          }
          float so = po.x + po.y; so += qp<0xB1>(so); so += qp<0x4E>(so);
          if (isk0) obuf[((t - 4) & 63) * NF + q] = rintf(so + bo_);
        }
        if (l >= 32) {
          const int j = l - 32;
          if ((t & 31) == 4 && t >= 36) {
            #pragma unroll
            for (int ii = 0; ii < 2; ++ii) {
              const int fidx = 2 * j + ii;
              const int s = (t - 36) + (fidx >> 1);
              const int c4 = (fidx & 1) * 4;
              *(f4*)&outp[s * NF + c4] = *(const f4*)&obuf[(s & 63) * NF + c4];
            }
          }
          if ((t & 31) == 12) {
            const int cl = (t >> 5) + 1;
            if (cl * 32 < T) {
              #pragma unroll
              for (int ii = 0; ii < 2; ++ii) {
                const int off = (2 * j + ii) * 4;
                *(f4*)&tbuf[cl & 1][off] = *(const f4*)&target[cl * 256 + off];
              }
            }
          }
        }
      }
    }
    // ---- release: own group's phase counter ----
    if (l == 0)
      __hip_atomic_fetch_add(&cnt[isL1 ? 1 : 0], 1, __ATOMIC_RELEASE,
                             __HIP_MEMORY_SCOPE_WORKGROUP);
    tgt += 4; tgtm += 4;
  }
  __syncthreads();

  // ================= EPILOGUE =================
  {
    const int s0 = ((T - 1) >> 5) << 5;   // last partial window
    for (int idx = tid; idx < (T - s0) * NF; idx += 512) {
      const int s = s0 + (idx >> 3);
      outp[s * NF + (idx & 7)] = obuf[(s & 63) * NF + (idx & 7)];
    }
  }
  if (isk0) {
    const int base = T * NF;
    if (!isL1) {
      outp[base + u]        = hS;   // h_final layer 0
      outp[base + 128 + u]  = cS;   // c_final layer 0
    } else {
      outp[base + 64 + u]   = hS;   // h_final layer 1
      outp[base + 192 + u]  = cS;   // c_final layer 1
    }
  }
}

extern "C" void kernel_launch(void* const* d_in, const int* in_sizes, int n_in,
                              void* d_out, int out_size, void* d_ws, size_t ws_size,
                              hipStream_t stream) {
  const float* h0in   = (const float*)d_in[1];
  const float* c0in   = (const float*)d_in[2];
  const float* diffp  = (const float*)d_in[3];
  const float* target = (const float*)d_in[4];
  const float* Wih0   = (const float*)d_in[5];
  const float* Whh0   = (const float*)d_in[6];
  const float* bih0   = (const float*)d_in[7];
  const float* bhh0   = (const float*)d_in[8];
  const float* Wih1   = (const float*)d_in[9];
  const float* Whh1   = (const float*)d_in[10];
  const float* bih1   = (const float*)d_in[11];
  const float* bhh1   = (const float*)d_in[12];
  const float* Whid   = (const float*)d_in[13];
  const float* bhidp  = (const float*)d_in[14];
  const float* Woutp  = (const float*)d_in[15];
  const float* boutp  = (const float*)d_in[16];
  float* outp = (float*)d_out;
  const int T = in_sizes[4] / NF;

  decoder_p7<<<dim3(1), dim3(512), 0, stream>>>(
      h0in, c0in, diffp, target,
      Wih0, Whh0, bih0, bhh0,
      Wih1, Whh1, bih1, bhh1,
      Whid, bhidp, Woutp, boutp,
      outp, T);
}